// Round 17
// baseline (644.829 us; speedup 1.0000x reference)
//
#include <hip/hip_runtime.h>
#include <math.h>
#include <stdint.h>

// ---------------------------------------------------------------------------
// CANA_nei graph network forward. bf16 MFMA GEMMs; CSR aggregation fused into
// the conv GEMM. Conv reads MFMA B-fragments directly from L2-resident W^T
// (no Bs LDS tile) -> conv LDS 17.4 KB -> ~2x gather occupancy.
// P-projection fused into producing epilogues; L0 edge attention fused into
// the CSR fill; L1 edge attention rides as trailing blocks of cf-conv(L0).
// Output layout: [10, N, 128] = [src1, xs_s0, xs_s1, trg1, xs_t0, xs_t1,
//                                cf_s0, cf_s1, cf_t0, cf_t1]
// ---------------------------------------------------------------------------

typedef __attribute__((ext_vector_type(8))) short bh8;   // 8 bf16 (4 VGPRs)
typedef __attribute__((ext_vector_type(4))) float f4;    // MFMA acc frag

__device__ __forceinline__ float relu_f(float x) { return x > 0.f ? x : 0.f; }

__device__ __forceinline__ unsigned short f2bf(float f) {
    union { float f; unsigned u; } v; v.f = f;
    unsigned r = v.u + 0x7FFF + ((v.u >> 16) & 1);   // RNE
    return (unsigned short)(r >> 16);
}
__device__ __forceinline__ float bf2f(unsigned short b) {
    union { unsigned u; float f; } v; v.u = ((unsigned)b) << 16;
    return v.f;
}

template<int ACT>
__device__ __forceinline__ float act_fn(float x) {
    if (ACT == 1) return 0.5f * x * (1.f + erff(x * 0.70710678118654752f)); // exact GELU
    if (ACT == 2) return x / (1.f + fabsf(x));                              // soft_sign
    return x;
}

// ---------------------------------------------------------------------------
// Shared edge-attention MLP body.
// ---------------------------------------------------------------------------
__device__ __forceinline__ float edge_att_mlp(const unsigned short* p1,
                                              const unsigned short* p2,
                                              const float* w2, const float* b2s,
                                              const float* w3s, const float* sb1,
                                              float sb3)
{
    bh8 a0 = *(const bh8*)&p1[0];
    bh8 a1 = *(const bh8*)&p1[8];
    ushort4 a2 = *(const ushort4*)&p1[16];
    bh8 b0 = *(const bh8*)&p2[0];
    bh8 b1 = *(const bh8*)&p2[8];
    ushort4 b2 = *(const ushort4*)&p2[16];

    float h1[20];
    #pragma unroll
    for (int j = 0; j < 8; ++j)
        h1[j] = relu_f(bf2f((unsigned short)a0[j]) + bf2f((unsigned short)b0[j]) + sb1[j]);
    #pragma unroll
    for (int j = 0; j < 8; ++j)
        h1[8 + j] = relu_f(bf2f((unsigned short)a1[j]) + bf2f((unsigned short)b1[j]) + sb1[8 + j]);
    h1[16] = relu_f(bf2f(a2.x) + bf2f(b2.x) + sb1[16]);
    h1[17] = relu_f(bf2f(a2.y) + bf2f(b2.y) + sb1[17]);
    h1[18] = relu_f(bf2f(a2.z) + bf2f(b2.z) + sb1[18]);
    h1[19] = relu_f(bf2f(a2.w) + bf2f(b2.w) + sb1[19]);

    float h3 = sb3;
    #pragma unroll
    for (int j2 = 0; j2 < 10; ++j2) {
        float s = b2s[j2];
        #pragma unroll
        for (int j = 0; j < 20; ++j)
            s = fmaf(h1[j], w2[j * 10 + j2], s);
        h3 = fmaf(relu_f(s), w3s[j2], h3);
    }
    h3 = relu_f(h3);
    return 1.f / (1.f + expf(-h3));
}

// ---------------------------------------------------------------------------
// P-emission phase: As holds xs bf16 [64][136]; W56 read directly from global.
// ---------------------------------------------------------------------------
__device__ __forceinline__ void emit_p_phase_g(const short* As,
                                               const short* __restrict__ W56,
                                               short* __restrict__ P,
                                               int row0, int M, int t)
{
    const int lane = t & 63, w = t >> 6, l15 = lane & 15, l4 = lane >> 4;
    f4 accP[4];
    #pragma unroll
    for (int ni = 0; ni < 4; ++ni) accP[ni] = (f4){0.f, 0.f, 0.f, 0.f};
    #pragma unroll
    for (int kk = 0; kk < 4; ++kk) {
        bh8 a = *(const bh8*)&As[(w * 16 + l15) * 136 + kk * 32 + l4 * 8];
        #pragma unroll
        for (int ni = 0; ni < 4; ++ni) {
            bh8 b = *(const bh8*)(W56 + (size_t)(ni * 16 + l15) * 128 + kk * 32 + l4 * 8);
            accP[ni] = __builtin_amdgcn_mfma_f32_16x16x32_bf16(a, b, accP[ni], 0, 0, 0);
        }
    }
    #pragma unroll
    for (int ni = 0; ni < 4; ++ni) {
        int col = ni * 16 + l15;
        #pragma unroll
        for (int r = 0; r < 4; ++r) {
            int row = row0 + w * 16 + l4 * 4 + r;
            if (row < M) P[(size_t)row * 64 + col] = (short)f2bf(accP[ni][r]);
        }
    }
}

// ---------------------------------------------------------------------------
// Plain MFMA GEMM, dual-graph: out[M,128] = act(X @ W + bias). (R12 form.)
// ---------------------------------------------------------------------------
template<int K, int AF, int ACT, bool BIAS, bool WF32, bool WB16, bool EMITP>
__global__ __launch_bounds__(256, 2)
void mfma_gemm(const void* __restrict__ X0a, const void* __restrict__ X0b,
               const short* __restrict__ W0t, const float* __restrict__ bias,
               float* __restrict__ outfA, short* __restrict__ outbA,
               float* __restrict__ outfB, short* __restrict__ outbB,
               const short* __restrict__ W56,
               short* __restrict__ PA, short* __restrict__ PB, int M)
{
    constexpr int BK  = 64;
    constexpr int LDA = EMITP ? 136 : 72;
    __shared__ short As[64 * LDA];
    __shared__ short Bs[128 * 72];

    const int half = gridDim.x >> 1;
    int bid = blockIdx.x;
    const int g1 = bid >= half;
    bid -= g1 ? half : 0;
    const void* X0v = g1 ? X0b : X0a;
    float* outf = g1 ? outfB : outfA;
    short* outb = g1 ? outbB : outbA;
    short* P    = g1 ? PB : PA;

    const int t    = threadIdx.x;
    const int row0 = bid * 64;
    const int lane = t & 63;
    const int w    = t >> 6;
    const int wr   = w & 1;
    const int wc   = w >> 1;
    const int l15  = lane & 15;
    const int l4   = lane >> 4;

    f4 acc[2][4];
    #pragma unroll
    for (int i = 0; i < 2; ++i)
        #pragma unroll
        for (int j = 0; j < 4; ++j)
            acc[i][j] = (f4){0.f, 0.f, 0.f, 0.f};

    const int ar = t >> 3;
    const int ac = (t & 7) * 8;

    #pragma unroll 1
    for (int k0 = 0; k0 < K; k0 += BK) {
        __syncthreads();
        #pragma unroll
        for (int p = 0; p < 2; ++p) {
            int r    = ar + p * 32;
            int grow = row0 + r;
            bh8 sv = {0, 0, 0, 0, 0, 0, 0, 0};
            if (AF == 0) {
                if (grow < M) {
                    const float* src = (const float*)X0v + (size_t)grow * K + k0 + ac;
                    float4 v0 = *(const float4*)src;
                    float4 v1 = *(const float4*)(src + 4);
                    sv[0] = (short)f2bf(v0.x); sv[1] = (short)f2bf(v0.y);
                    sv[2] = (short)f2bf(v0.z); sv[3] = (short)f2bf(v0.w);
                    sv[4] = (short)f2bf(v1.x); sv[5] = (short)f2bf(v1.y);
                    sv[6] = (short)f2bf(v1.z); sv[7] = (short)f2bf(v1.w);
                }
            } else {
                if (grow < M)
                    sv = *(const bh8*)((const short*)X0v + (size_t)grow * K + k0 + ac);
            }
            *(bh8*)&As[r * LDA + ac] = sv;
        }
        #pragma unroll
        for (int p = 0; p < 4; ++p) {
            int r = ar + p * 32;
            *(bh8*)&Bs[r * 72 + ac] = *(const bh8*)(W0t + (size_t)r * K + k0 + ac);
        }
        __syncthreads();
        #pragma unroll
        for (int kk = 0; kk < 2; ++kk) {
            bh8 a[2], b[4];
            #pragma unroll
            for (int mi = 0; mi < 2; ++mi)
                a[mi] = *(const bh8*)&As[(wr*32 + mi*16 + l15) * LDA + kk*32 + l4*8];
            #pragma unroll
            for (int ni = 0; ni < 4; ++ni)
                b[ni] = *(const bh8*)&Bs[(wc*64 + ni*16 + l15) * 72 + kk*32 + l4*8];
            #pragma unroll
            for (int mi = 0; mi < 2; ++mi)
                #pragma unroll
                for (int ni = 0; ni < 4; ++ni)
                    acc[mi][ni] = __builtin_amdgcn_mfma_f32_16x16x32_bf16(
                        a[mi], b[ni], acc[mi][ni], 0, 0, 0);
        }
    }

    if (EMITP) __syncthreads();
    #pragma unroll
    for (int mi = 0; mi < 2; ++mi) {
        #pragma unroll
        for (int ni = 0; ni < 4; ++ni) {
            int col = wc * 64 + ni * 16 + l15;
            float bv = BIAS ? bias[col] : 0.f;
            #pragma unroll
            for (int r = 0; r < 4; ++r) {
                int rloc = wr * 32 + mi * 16 + l4 * 4 + r;
                int row  = row0 + rloc;
                float v = act_fn<ACT>(acc[mi][ni][r] + bv);
                unsigned short bb = f2bf(v);
                if (row < M) {
                    if (WF32) outf[(size_t)row * 128 + col] = v;
                    if (WB16) outb[(size_t)row * 128 + col] = (short)bb;
                }
                if (EMITP) As[rloc * LDA + col] = (short)bb;
            }
        }
    }
    if (EMITP) {
        __syncthreads();
        emit_p_phase_g(As, W56, P, row0, M, t);
    }
}

// ---------------------------------------------------------------------------
// Fused GraphConv: out = softsign(x @ Wroot + agg @ Wrel), dual-graph.
// No Bs tile: MFMA B-fragments read directly from L2-resident W^T.
// LDS = As only (17.4 KB) -> ~2x occupancy for the latency-bound gather.
// Gather: per-node straight-line loads, 8-deep ILP (R12 ladder, bit-exact).
// DOATT: trailing blocks run the next layer's edge attention.
// ---------------------------------------------------------------------------
template<int MODE, bool WB16, bool EMITP, bool DOATT>
__global__ __launch_bounds__(256, 2)
void conv_fused(const short* __restrict__ XbA, const short* __restrict__ XbB,
                const int* __restrict__ coffA, const int* __restrict__ coffB,
                const int* __restrict__ crowA, const int* __restrict__ crowB,
                const float* __restrict__ attcA, const float* __restrict__ attcB,
                const short* __restrict__ Wroot, const short* __restrict__ Wrel,
                const short* __restrict__ W56,
                float* __restrict__ outfA, float* __restrict__ outfB,
                short* __restrict__ outbA, short* __restrict__ outbB,
                short* __restrict__ PA, short* __restrict__ PB,
                int convBlocks,
                const int* __restrict__ rowS, const int* __restrict__ colS,
                const int* __restrict__ rowT, const int* __restrict__ colT,
                const int* __restrict__ eposS, const int* __restrict__ eposT,
                const short* __restrict__ PinS, const short* __restrict__ PinT,
                const float* __restrict__ eab1, const float* __restrict__ eaW2,
                const float* __restrict__ eab2, const float* __restrict__ eaW3,
                const float* __restrict__ eab3,
                float* __restrict__ attOutS, float* __restrict__ attOutT,
                int E, int M)
{
    constexpr int LDA = 136;             // full-K agg tile [64][136]
    __shared__ short As[64 * LDA];

    const int t = threadIdx.x;

    // ---- Attention branch (trailing blocks, DOATT only) ----
    if (DOATT && (int)blockIdx.x >= convBlocks) {
        float* ea = (float*)As;          // reuse LDS: 241 floats
        if (t < 200)       ea[t] = eaW2[t];
        else if (t < 210)  ea[t] = eab2[t - 200];
        else if (t < 220)  ea[t] = eaW3[t - 210];
        else if (t < 240)  ea[t] = eab1[t - 220];
        else if (t == 240) ea[240] = eab3[0];
        __syncthreads();
        int idx = ((int)blockIdx.x - convBlocks) * 256 + t;
        if (idx < 2 * E) {
            const int g1 = idx >= E;
            const int e  = idx - (g1 ? E : 0);
            const int* row  = g1 ? rowT  : rowS;
            const int* col  = g1 ? colT  : colS;
            const int* epos = g1 ? eposT : eposS;
            const short* P  = g1 ? PinT  : PinS;
            float* attOut   = g1 ? attOutT : attOutS;
            int r = row[e], c = col[e];
            const unsigned short* p1 = (const unsigned short*)P + (size_t)r * 64;
            const unsigned short* p2 = (const unsigned short*)P + (size_t)c * 64 + 32;
            attOut[epos[e]] = edge_att_mlp(p1, p2, ea, ea + 200, ea + 210, ea + 220, ea[240]);
        }
        return;
    }

    const int half = convBlocks >> 1;
    int bid = blockIdx.x;
    const int g1 = bid >= half;
    bid -= g1 ? half : 0;
    const short* Xb   = g1 ? XbB   : XbA;
    const int*   coff = g1 ? coffB : coffA;
    const int*   crow = g1 ? crowB : crowA;
    const float* attc = g1 ? attcB : attcA;
    float* outf = g1 ? outfB : outfA;
    short* outb = g1 ? outbB : outbA;
    short* P    = g1 ? PB : PA;

    const int row0 = bid * 64;
    const int lane = t & 63;
    const int w    = t >> 6;
    const int wr   = w & 1;
    const int wc   = w >> 1;
    const int l15  = lane & 15;
    const int l4   = lane >> 4;

    // ---- Phase 1: CSR gather, per-node 8-deep straight-line ILP ----
    {
        const int g  = t >> 4;           // 16 groups of 16 lanes
        const int li = t & 15;
        #pragma unroll 1
        for (int q = 0; q < 4; ++q) {
            int rloc = g * 4 + q;
            int n = row0 + rloc;
            float a8[8] = {0.f, 0.f, 0.f, 0.f, 0.f, 0.f, 0.f, 0.f};
            if (n < M) {
                int p  = coff[n];
                int pe = coff[n + 1];
                for (; p + 7 < pe; p += 8) {
                    float w0 = attc[p],     w1 = attc[p + 1];
                    float w2 = attc[p + 2], w3 = attc[p + 3];
                    float w4 = attc[p + 4], w5 = attc[p + 5];
                    float w6 = attc[p + 6], w7 = attc[p + 7];
                    int r0 = crow[p],     r1 = crow[p + 1];
                    int r2 = crow[p + 2], r3 = crow[p + 3];
                    int r4 = crow[p + 4], r5 = crow[p + 5];
                    int r6 = crow[p + 6], r7 = crow[p + 7];
                    w0 = MODE ? fmaf(-0.5f, w0, 1.f) : 0.5f * w0;
                    w1 = MODE ? fmaf(-0.5f, w1, 1.f) : 0.5f * w1;
                    w2 = MODE ? fmaf(-0.5f, w2, 1.f) : 0.5f * w2;
                    w3 = MODE ? fmaf(-0.5f, w3, 1.f) : 0.5f * w3;
                    w4 = MODE ? fmaf(-0.5f, w4, 1.f) : 0.5f * w4;
                    w5 = MODE ? fmaf(-0.5f, w5, 1.f) : 0.5f * w5;
                    w6 = MODE ? fmaf(-0.5f, w6, 1.f) : 0.5f * w6;
                    w7 = MODE ? fmaf(-0.5f, w7, 1.f) : 0.5f * w7;
                    bh8 v0 = *(const bh8*)&Xb[(size_t)r0 * 128 + li * 8];
                    bh8 v1 = *(const bh8*)&Xb[(size_t)r1 * 128 + li * 8];
                    bh8 v2 = *(const bh8*)&Xb[(size_t)r2 * 128 + li * 8];
                    bh8 v3 = *(const bh8*)&Xb[(size_t)r3 * 128 + li * 8];
                    bh8 v4 = *(const bh8*)&Xb[(size_t)r4 * 128 + li * 8];
                    bh8 v5 = *(const bh8*)&Xb[(size_t)r5 * 128 + li * 8];
                    bh8 v6 = *(const bh8*)&Xb[(size_t)r6 * 128 + li * 8];
                    bh8 v7 = *(const bh8*)&Xb[(size_t)r7 * 128 + li * 8];
                    #pragma unroll
                    for (int j = 0; j < 8; ++j) {
                        a8[j] = fmaf(w0, bf2f((unsigned short)v0[j]), a8[j]);
                        a8[j] = fmaf(w1, bf2f((unsigned short)v1[j]), a8[j]);
                        a8[j] = fmaf(w2, bf2f((unsigned short)v2[j]), a8[j]);
                        a8[j] = fmaf(w3, bf2f((unsigned short)v3[j]), a8[j]);
                        a8[j] = fmaf(w4, bf2f((unsigned short)v4[j]), a8[j]);
                        a8[j] = fmaf(w5, bf2f((unsigned short)v5[j]), a8[j]);
                        a8[j] = fmaf(w6, bf2f((unsigned short)v6[j]), a8[j]);
                        a8[j] = fmaf(w7, bf2f((unsigned short)v7[j]), a8[j]);
                    }
                }
                for (; p + 3 < pe; p += 4) {
                    float w0 = attc[p],     w1 = attc[p + 1];
                    float w2 = attc[p + 2], w3 = attc[p + 3];
                    int r0 = crow[p],     r1 = crow[p + 1];
                    int r2 = crow[p + 2], r3 = crow[p + 3];
                    w0 = MODE ? fmaf(-0.5f, w0, 1.f) : 0.5f * w0;
                    w1 = MODE ? fmaf(-0.5f, w1, 1.f) : 0.5f * w1;
                    w2 = MODE ? fmaf(-0.5f, w2, 1.f) : 0.5f * w2;
                    w3 = MODE ? fmaf(-0.5f, w3, 1.f) : 0.5f * w3;
                    bh8 v0 = *(const bh8*)&Xb[(size_t)r0 * 128 + li * 8];
                    bh8 v1 = *(const bh8*)&Xb[(size_t)r1 * 128 + li * 8];
                    bh8 v2 = *(const bh8*)&Xb[(size_t)r2 * 128 + li * 8];
                    bh8 v3 = *(const bh8*)&Xb[(size_t)r3 * 128 + li * 8];
                    #pragma unroll
                    for (int j = 0; j < 8; ++j) {
                        a8[j] = fmaf(w0, bf2f((unsigned short)v0[j]), a8[j]);
                        a8[j] = fmaf(w1, bf2f((unsigned short)v1[j]), a8[j]);
                        a8[j] = fmaf(w2, bf2f((unsigned short)v2[j]), a8[j]);
                        a8[j] = fmaf(w3, bf2f((unsigned short)v3[j]), a8[j]);
                    }
                }
                for (; p < pe; ++p) {
                    float w0 = attc[p];
                    int   r0 = crow[p];
                    w0 = MODE ? fmaf(-0.5f, w0, 1.f) : 0.5f * w0;
                    bh8 v0 = *(const bh8*)&Xb[(size_t)r0 * 128 + li * 8];
                    #pragma unroll
                    for (int j = 0; j < 8; ++j)
                        a8[j] = fmaf(w0, bf2f((unsigned short)v0[j]), a8[j]);
                }
            }
            bh8 o;
            #pragma unroll
            for (int j = 0; j < 8; ++j) o[j] = (short)f2bf(a8[j]);
            *(bh8*)&As[rloc * LDA + li * 8] = o;
        }
    }
    __syncthreads();

    f4 acc[2][4];
    #pragma unroll
    for (int i = 0; i < 2; ++i)
        #pragma unroll
        for (int j = 0; j < 4; ++j)
            acc[i][j] = (f4){0.f, 0.f, 0.f, 0.f};

    // ---- Phase 2: agg @ Wrel (B-frags direct from global; As stable) ----
    #pragma unroll
    for (int k0 = 0; k0 < 128; k0 += 64) {
        #pragma unroll
        for (int kk = 0; kk < 2; ++kk) {
            bh8 a[2], b[4];
            #pragma unroll
            for (int mi = 0; mi < 2; ++mi)
                a[mi] = *(const bh8*)&As[(wr*32 + mi*16 + l15) * LDA + k0 + kk*32 + l4*8];
            #pragma unroll
            for (int ni = 0; ni < 4; ++ni)
                b[ni] = *(const bh8*)(Wrel + (size_t)(wc*64 + ni*16 + l15) * 128 + k0 + kk*32 + l4*8);
            #pragma unroll
            for (int mi = 0; mi < 2; ++mi)
                #pragma unroll
                for (int ni = 0; ni < 4; ++ni)
                    acc[mi][ni] = __builtin_amdgcn_mfma_f32_16x16x32_bf16(
                        a[mi], b[ni], acc[mi][ni], 0, 0, 0);
        }
    }
    __syncthreads();

    // ---- Phase 3: restage As with x rows (linear), then x @ Wroot ----
    {
        const int r0l = t >> 4;          // 0..15
        const int c   = (t & 15) * 8;    // 0..120
        #pragma unroll
        for (int p = 0; p < 4; ++p) {
            int r    = r0l + p * 16;
            int grow = row0 + r;
            bh8 sv = {0, 0, 0, 0, 0, 0, 0, 0};
            if (grow < M)
                sv = *(const bh8*)(Xb + (size_t)grow * 128 + c);
            *(bh8*)&As[r * LDA + c] = sv;
        }
    }
    __syncthreads();
    #pragma unroll
    for (int k0 = 0; k0 < 128; k0 += 64) {
        #pragma unroll
        for (int kk = 0; kk < 2; ++kk) {
            bh8 a[2], b[4];
            #pragma unroll
            for (int mi = 0; mi < 2; ++mi)
                a[mi] = *(const bh8*)&As[(wr*32 + mi*16 + l15) * LDA + k0 + kk*32 + l4*8];
            #pragma unroll
            for (int ni = 0; ni < 4; ++ni)
                b[ni] = *(const bh8*)(Wroot + (size_t)(wc*64 + ni*16 + l15) * 128 + k0 + kk*32 + l4*8);
            #pragma unroll
            for (int mi = 0; mi < 2; ++mi)
                #pragma unroll
                for (int ni = 0; ni < 4; ++ni)
                    acc[mi][ni] = __builtin_amdgcn_mfma_f32_16x16x32_bf16(
                        a[mi], b[ni], acc[mi][ni], 0, 0, 0);
        }
    }

    // ---- Epilogue (+ optional P emission) ----
    if (EMITP) __syncthreads();
    #pragma unroll
    for (int mi = 0; mi < 2; ++mi) {
        #pragma unroll
        for (int ni = 0; ni < 4; ++ni) {
            int col = wc * 64 + ni * 16 + l15;
            #pragma unroll
            for (int r = 0; r < 4; ++r) {
                int rloc = wr * 32 + mi * 16 + l4 * 4 + r;
                int row  = row0 + rloc;
                float v = act_fn<2>(acc[mi][ni][r]);
                unsigned short bb = f2bf(v);
                if (row < M) {
                    outf[(size_t)row * 128 + col] = v;
                    if (WB16) outb[(size_t)row * 128 + col] = (short)bb;
                }
                if (EMITP) As[rloc * LDA + col] = (short)bb;
            }
        }
    }
    if (EMITP) {
        __syncthreads();
        emit_p_phase_g(As, W56, P, row0, M, t);
    }
}

// ---------------------------------------------------------------------------
// Weight prep + degree histogram, one dispatch (independent block ranges).
// ---------------------------------------------------------------------------
__global__ void prep_hist(const float* __restrict__ eaW1, const float* __restrict__ fxW1,
                          const float* __restrict__ fxW2, const float* __restrict__ convWroot,
                          const float* __restrict__ convWrel,
                          short* __restrict__ w56, short* __restrict__ fxW1t,
                          short* __restrict__ fxW2t, short* __restrict__ wrt,
                          short* __restrict__ wlt,
                          const int* __restrict__ colS, const int* __restrict__ colT,
                          int* __restrict__ deg, int N, int E, int prepBlocks)
{
    if ((int)blockIdx.x >= prepBlocks) {
        int idx = (blockIdx.x - prepBlocks) * 256 + threadIdx.x;
        if (idx >= 2 * E) return;
        const int g1 = idx >= E;
        const int e  = idx - (g1 ? E : 0);
        int c = (g1 ? colT : colS)[e];
        atomicAdd(&deg[(size_t)g1 * N + c], 1);
        return;
    }
    int i = blockIdx.x * 256 + threadIdx.x;
    if (i < 64 * 128) {
        int j = i >> 7, k = i & 127;
        float v = 0.f;
        if (j < 20)                  v = eaW1[k * 20 + j];
        else if (j >= 32 && j < 52)  v = eaW1[(128 + k) * 20 + (j - 32)];
        w56[i] = (short)f2bf(v);
        return;
    }
    i -= 64 * 128;
    if (i < 512 * 128) {
        int k = i >> 7, n = i & 127;
        fxW1t[(size_t)n * 512 + k] = (short)f2bf(fxW1[i]);
        return;
    }
    i -= 512 * 128;
    if (i < 128 * 128) {
        int k = i >> 7, n = i & 127;
        fxW2t[n * 128 + k] = (short)f2bf(fxW2[i]);
        return;
    }
    i -= 128 * 128;
    if (i < 2 * 128 * 128) {
        int L = i >> 14, r = i & 16383;
        int k = r >> 7, n = r & 127;
        wrt[L * 16384 + n * 128 + k] = (short)f2bf(convWroot[i]);
        return;
    }
    i -= 2 * 128 * 128;
    if (i < 2 * 128 * 128) {
        int L = i >> 14, r = i & 16383;
        int k = r >> 7, n = r & 127;
        wlt[L * 16384 + n * 128 + k] = (short)f2bf(convWrel[i]);
    }
}

// ---------------------------------------------------------------------------
// CSR build: scan kernels (hist lives in prep_hist)
// ---------------------------------------------------------------------------
__device__ __forceinline__ int block_incl_scan(int v, int* wsum)
{
    int lane = threadIdx.x & 63;
    int w    = threadIdx.x >> 6;
    #pragma unroll
    for (int off = 1; off < 64; off <<= 1) {
        int t = __shfl_up(v, off);
        if (lane >= off) v += t;
    }
    if (lane == 63) wsum[w] = v;
    __syncthreads();
    int add = 0;
    for (int j = 0; j < w; ++j) add += wsum[j];
    return v + add;
}

__global__ __launch_bounds__(256)
void scanA_both(const int* __restrict__ deg, int* __restrict__ coffS,
                int* __restrict__ coffT, int* __restrict__ bsum, int N)
{
    __shared__ int wsum[4];
    int gy = blockIdx.y;
    const int* d = deg + (size_t)gy * N;
    int* coff    = gy ? coffT : coffS;
    int* bs      = bsum + gy * 256;
    int i = blockIdx.x * 256 + threadIdx.x;
    int orig = (i < N) ? d[i] : 0;
    int v = block_incl_scan(orig, wsum);
    if (i < N) coff[i] = v - orig;
    if (threadIdx.x == 255) bs[blockIdx.x] = v;
}

__global__ __launch_bounds__(256)
void scanB_both(const int* __restrict__ bsum, int* __restrict__ boff, int nb)
{
    __shared__ int wsum[4];
    int gy = blockIdx.y;
    const int* bs = bsum + gy * 256;
    int* bo       = boff + gy * 256;
    int tid = threadIdx.x;
    int orig = (tid < nb) ? bs[tid] : 0;
    int v = block_incl_scan(orig, wsum);
    if (tid < nb) bo[tid] = v - orig;
}

__global__ __launch_bounds__(256)
void scanC_both(int* __restrict__ coffS, int* __restrict__ coffT,
                const int* __restrict__ boff, int* __restrict__ curS,
                int* __restrict__ curT, int N, int E)
{
    int gy = blockIdx.y;
    int* coff = gy ? coffT : coffS;
    int* cur  = gy ? curT  : curS;
    const int* bo = boff + gy * 256;
    int i = blockIdx.x * 256 + threadIdx.x;
    if (i < N) {
        int v = coff[i] + bo[i >> 8];
        coff[i] = v;
        cur[i]  = v;
    }
    if (i == 0) coff[N] = E;
}

// ---------------------------------------------------------------------------
// CSR cursor fill + L0 edge attention, fused.
// ---------------------------------------------------------------------------
__global__ __launch_bounds__(256)
void fill_att_both(const int* __restrict__ rowS, const int* __restrict__ colS,
                   const int* __restrict__ rowT, const int* __restrict__ colT,
                   int* __restrict__ curS, int* __restrict__ curT,
                   int* __restrict__ crowS, int* __restrict__ crowT,
                   int* __restrict__ eposS, int* __restrict__ eposT,
                   const short* __restrict__ PS, const short* __restrict__ PT,
                   const float* __restrict__ eab1, const float* __restrict__ eaW2,
                   const float* __restrict__ eab2, const float* __restrict__ eaW3,
                   const float* __restrict__ eab3,
                   float* __restrict__ attcS, float* __restrict__ attcT, int E)
{
    __shared__ float w2[200], b2s[10], w3s[10], sb1[20], sb3;
    int t = threadIdx.x;
    if (t < 200) w2[t] = eaW2[t];
    if (t < 20)  sb1[t] = eab1[t];
    if (t < 10)  { b2s[t] = eab2[t]; w3s[t] = eaW3[t]; }
    if (t == 0)  sb3 = eab3[0];
    __syncthreads();

    int idx = blockIdx.x * 256 + t;
    if (idx >= 2 * E) return;
    const int g1 = idx >= E;
    const int e  = idx - (g1 ? E : 0);
    const int* row = g1 ? rowT : rowS;
    const int* col = g1 ? colT : colS;
    int* cur  = g1 ? curT  : curS;
    int* crow = g1 ? crowT : crowS;
    int* epos = g1 ? eposT : eposS;
    const short* P = g1 ? PT : PS;
    float* attc    = g1 ? attcT : attcS;

    int c = col[e];
    int r = row[e];
    int p = atomicAdd(&cur[c], 1);
    crow[p] = r;
    epos[e] = p;

    const unsigned short* p1 = (const unsigned short*)P + (size_t)r * 64;
    const unsigned short* p2 = (const unsigned short*)P + (size_t)c * 64 + 32;
    attc[p] = edge_att_mlp(p1, p2, w2, b2s, w3s, sb1, sb3);
}

// ---------------------------------------------------------------------------

extern "C" void kernel_launch(void* const* d_in, const int* in_sizes, int n_in,
                              void* d_out, int out_size, void* d_ws, size_t ws_size,
                              hipStream_t stream)
{
    const float* src_fea = (const float*)d_in[0];
    const float* trg_fea = (const float*)d_in[1];
    const int*   src_row = (const int*)d_in[2];
    const int*   src_col = (const int*)d_in[3];
    const int*   trg_row = (const int*)d_in[4];
    const int*   trg_col = (const int*)d_in[5];
    const float* fxW1 = (const float*)d_in[6];
    const float* fxb1 = (const float*)d_in[7];
    const float* fxW2 = (const float*)d_in[8];
    const float* fxb2 = (const float*)d_in[9];
    const float* eaW1 = (const float*)d_in[10];
    const float* eab1 = (const float*)d_in[11];
    const float* eaW2 = (const float*)d_in[12];
    const float* eab2 = (const float*)d_in[13];
    const float* eaW3 = (const float*)d_in[14];
    const float* eab3 = (const float*)d_in[15];
    const float* convWroot = (const float*)d_in[16];
    const float* convWrel  = (const float*)d_in[17];

    const int N = in_sizes[0] / 512;
    const int E = in_sizes[2];

    float* out = (float*)d_out;
    const size_t slot_sz = (size_t)N * 128;
    auto slot = [&](int i) { return out + (size_t)i * slot_sz; };

    // ---- workspace layout ----
    float* fp     = (float*)d_ws;
    float* attcS0 = fp; fp += E;
    float* attcT0 = fp; fp += E;
    float* attcS1 = fp; fp += E;
    float* attcT1 = fp; fp += E;
    int* ip    = (int*)fp;
    int* deg   = ip; ip += 2 * N;
    int* bsum  = ip; ip += 512;
    int* boff  = ip; ip += 512;
    int* coffS = ip; ip += N + 2;
    int* coffT = ip; ip += N + 2;
    int* curS  = ip; ip += N;
    int* curT  = ip; ip += N;
    int* crowS = ip; ip += E;
    int* crowT = ip; ip += E;
    int* eposS = ip; ip += E;
    int* eposT = ip; ip += E;
    short* sp = (short*)((((uintptr_t)ip) + 255) & ~(uintptr_t)255);
    short* xb0   = sp; sp += slot_sz;            // bf16 src1
    short* xb1   = sp; sp += slot_sz;            // bf16 trg1
    short* xsbS[2]; short* xsbT[2];
    xsbS[0] = sp; sp += slot_sz;
    xsbS[1] = sp; sp += slot_sz;
    xsbT[0] = sp; sp += slot_sz;
    xsbT[1] = sp; sp += slot_sz;
    short* PS    = sp; sp += (size_t)N * 64;     // bf16 projections, stride 64
    short* PT    = sp; sp += (size_t)N * 64;
    short* w56   = sp; sp += 64 * 128;
    short* fxW1t = sp; sp += 128 * 512;
    short* fxW2t = sp; sp += 128 * 128;
    short* wrt   = sp; sp += 2 * 128 * 128;
    short* wlt   = sp; sp += 2 * 128 * 128;

    const int e2grid  = (2 * E + 255) / 256;
    const int nchunks = (N + 255) / 256;

    // ---- weight prep + degree histogram (one dispatch; deg zeroed first) ----
    hipMemsetAsync(deg, 0, (size_t)2 * N * sizeof(int), stream);
    const int prep_total = 64*128 + 512*128 + 128*128 + 2*128*128 + 2*128*128;
    const int prepBlocks = (prep_total + 255) / 256;
    prep_hist<<<prepBlocks + e2grid, 256, 0, stream>>>(
        eaW1, fxW1, fxW2, convWroot, convWrel, w56, fxW1t, fxW2t, wrt, wlt,
        src_col, trg_col, deg, N, E, prepBlocks);

    const int gb = (N + 63) / 64;
    short* hS = xsbS[0];   // fx hidden, dead until L0 conv writes
    short* hT = xsbT[0];
    // fx layer 1 (fp32 in, bf16 h out)
    mfma_gemm<512, 0, 1, true, false, true, false><<<2 * gb, 256, 0, stream>>>(
        src_fea, trg_fea, fxW1t, fxb1,
        nullptr, hS, nullptr, hT, nullptr, nullptr, nullptr, N);
    // fx layer 2 (+ emit P for L0 attention)
    mfma_gemm<128, 1, 1, true, true, true, true><<<2 * gb, 256, 0, stream>>>(
        hS, hT, fxW2t, fxb2,
        slot(0), xb0, slot(3), xb1, w56, PS, PT, N);

    // ---- CSR scan + fused fill/att(L0), both graphs ----
    scanA_both<<<dim3(nchunks, 2), 256, 0, stream>>>(deg, coffS, coffT, bsum, N);
    scanB_both<<<dim3(1, 2), 256, 0, stream>>>(bsum, boff, nchunks);
    scanC_both<<<dim3(nchunks, 2), 256, 0, stream>>>(coffS, coffT, boff, curS, curT, N, E);
    fill_att_both<<<e2grid, 256, 0, stream>>>(
        src_row, src_col, trg_row, trg_col, curS, curT, crowS, crowT,
        eposS, eposT, PS, PT, eab1, eaW2, eab2, eaW3, eab3, attcS0, attcT0, E);

    const short* WrT0 = wrt;
    const short* WlT0 = wlt;
    const short* WrT1 = wrt + 16384;
    const short* WlT1 = wlt + 16384;

    // ---- Layer 0 ----
    // xs0 = softsign(x @ Wroot0 + agg_wc(attc0) @ Wrel0); emits P(xs0)
    conv_fused<0, true, true, false><<<2 * gb, 256, 0, stream>>>(
        xb0, xb1, coffS, coffT, crowS, crowT, attcS0, attcT0,
        WrT0, WlT0, w56, slot(1), slot(4), xsbS[0], xsbT[0], PS, PT,
        2 * gb, nullptr, nullptr, nullptr, nullptr, nullptr, nullptr,
        nullptr, nullptr, nullptr, nullptr, nullptr, nullptr, nullptr,
        nullptr, nullptr, E, N);

    // cf0 = softsign(xs0 @ Wroot0 + agg_wo(attc0) @ Wrel0)
    //   + trailing blocks: edge attention for L1 from P(xs0) -> attc1
    conv_fused<1, false, false, true><<<2 * gb + e2grid, 256, 0, stream>>>(
        xsbS[0], xsbT[0], coffS, coffT, crowS, crowT, attcS0, attcT0,
        WrT0, WlT0, nullptr, slot(6), slot(8), nullptr, nullptr, nullptr, nullptr,
        2 * gb, src_row, src_col, trg_row, trg_col, eposS, eposT,
        PS, PT, eab1, eaW2, eab2, eaW3, eab3, attcS1, attcT1, E, N);

    // ---- Layer 1 ----
    // xs1 = softsign(xs0 @ Wroot1 + agg_wc(attc1) @ Wrel1)
    conv_fused<0, true, false, false><<<2 * gb, 256, 0, stream>>>(
        xsbS[0], xsbT[0], coffS, coffT, crowS, crowT, attcS1, attcT1,
        WrT1, WlT1, nullptr, slot(2), slot(5), xsbS[1], xsbT[1], nullptr, nullptr,
        2 * gb, nullptr, nullptr, nullptr, nullptr, nullptr, nullptr,
        nullptr, nullptr, nullptr, nullptr, nullptr, nullptr, nullptr,
        nullptr, nullptr, E, N);

    // cf1 = softsign(xs1 @ Wroot1 + agg_wo(attc1) @ Wrel1)
    conv_fused<1, false, false, false><<<2 * gb, 256, 0, stream>>>(
        xsbS[1], xsbT[1], coffS, coffT, crowS, crowT, attcS1, attcT1,
        WrT1, WlT1, nullptr, slot(7), slot(9), nullptr, nullptr, nullptr, nullptr,
        2 * gb, nullptr, nullptr, nullptr, nullptr, nullptr, nullptr,
        nullptr, nullptr, nullptr, nullptr, nullptr, nullptr, nullptr,
        nullptr, nullptr, E, N);
}

// Round 18
// 587.708 us; speedup vs baseline: 1.0972x; 1.0972x over previous
//
#include <hip/hip_runtime.h>
#include <math.h>
#include <stdint.h>

// ---------------------------------------------------------------------------
// CANA_nei graph network forward. bf16 MFMA GEMMs; CSR aggregation fused into
// the conv GEMM; P-projection fused into the producing GEMM's epilogue;
// L0 edge attention fused into the CSR fill; L1 edge attention runs as
// trailing blocks of the cf-conv(L0) dispatch. (R12 configuration — session
// best: 592.6 us, absmax 0.02006912.)
// Output layout: [10, N, 128] = [src1, xs_s0, xs_s1, trg1, xs_t0, xs_t1,
//                                cf_s0, cf_s1, cf_t0, cf_t1]
// ---------------------------------------------------------------------------

typedef __attribute__((ext_vector_type(8))) short bh8;   // 8 bf16 (4 VGPRs)
typedef __attribute__((ext_vector_type(4))) float f4;    // MFMA acc frag

__device__ __forceinline__ float relu_f(float x) { return x > 0.f ? x : 0.f; }

__device__ __forceinline__ unsigned short f2bf(float f) {
    union { float f; unsigned u; } v; v.f = f;
    unsigned r = v.u + 0x7FFF + ((v.u >> 16) & 1);   // RNE
    return (unsigned short)(r >> 16);
}
__device__ __forceinline__ float bf2f(unsigned short b) {
    union { unsigned u; float f; } v; v.u = ((unsigned)b) << 16;
    return v.f;
}

template<int ACT>
__device__ __forceinline__ float act_fn(float x) {
    if (ACT == 1) return 0.5f * x * (1.f + erff(x * 0.70710678118654752f)); // exact GELU
    if (ACT == 2) return x / (1.f + fabsf(x));                              // soft_sign
    return x;
}

// ---------------------------------------------------------------------------
// Shared edge-attention MLP body (identical FMA order everywhere it's used).
// ---------------------------------------------------------------------------
__device__ __forceinline__ float edge_att_mlp(const unsigned short* p1,
                                              const unsigned short* p2,
                                              const float* w2, const float* b2s,
                                              const float* w3s, const float* sb1,
                                              float sb3)
{
    bh8 a0 = *(const bh8*)&p1[0];
    bh8 a1 = *(const bh8*)&p1[8];
    ushort4 a2 = *(const ushort4*)&p1[16];
    bh8 b0 = *(const bh8*)&p2[0];
    bh8 b1 = *(const bh8*)&p2[8];
    ushort4 b2 = *(const ushort4*)&p2[16];

    float h1[20];
    #pragma unroll
    for (int j = 0; j < 8; ++j)
        h1[j] = relu_f(bf2f((unsigned short)a0[j]) + bf2f((unsigned short)b0[j]) + sb1[j]);
    #pragma unroll
    for (int j = 0; j < 8; ++j)
        h1[8 + j] = relu_f(bf2f((unsigned short)a1[j]) + bf2f((unsigned short)b1[j]) + sb1[8 + j]);
    h1[16] = relu_f(bf2f(a2.x) + bf2f(b2.x) + sb1[16]);
    h1[17] = relu_f(bf2f(a2.y) + bf2f(b2.y) + sb1[17]);
    h1[18] = relu_f(bf2f(a2.z) + bf2f(b2.z) + sb1[18]);
    h1[19] = relu_f(bf2f(a2.w) + bf2f(b2.w) + sb1[19]);

    float h3 = sb3;
    #pragma unroll
    for (int j2 = 0; j2 < 10; ++j2) {
        float s = b2s[j2];
        #pragma unroll
        for (int j = 0; j < 20; ++j)
            s = fmaf(h1[j], w2[j * 10 + j2], s);
        h3 = fmaf(relu_f(s), w3s[j2], h3);
    }
    h3 = relu_f(h3);
    return 1.f / (1.f + expf(-h3));
}

// ---------------------------------------------------------------------------
// P-emission phase: As holds xs bf16 [64][136] (A layout), stages W56 into
// Bs, computes P = xs @ W56^T, writes P bf16 stride 64.
// ---------------------------------------------------------------------------
__device__ __forceinline__ void emit_p_phase(short* As, short* Bs,
                                             const short* __restrict__ W56,
                                             short* __restrict__ P,
                                             int row0, int M, int t)
{
    #pragma unroll
    for (int p = 0; p < 4; ++p) {
        int idx = t + 256 * p;            // 0..1023
        int r = idx >> 4;                 // 0..63
        int c = (idx & 15) * 8;           // 0..120
        *(bh8*)&Bs[r * 136 + c] = *(const bh8*)(W56 + r * 128 + c);
    }
    __syncthreads();
    const int lane = t & 63, w = t >> 6, l15 = lane & 15, l4 = lane >> 4;
    f4 accP[4];
    #pragma unroll
    for (int ni = 0; ni < 4; ++ni) accP[ni] = (f4){0.f, 0.f, 0.f, 0.f};
    #pragma unroll
    for (int kk = 0; kk < 4; ++kk) {
        bh8 a = *(const bh8*)&As[(w * 16 + l15) * 136 + kk * 32 + l4 * 8];
        #pragma unroll
        for (int ni = 0; ni < 4; ++ni) {
            bh8 b = *(const bh8*)&Bs[(ni * 16 + l15) * 136 + kk * 32 + l4 * 8];
            accP[ni] = __builtin_amdgcn_mfma_f32_16x16x32_bf16(a, b, accP[ni], 0, 0, 0);
        }
    }
    #pragma unroll
    for (int ni = 0; ni < 4; ++ni) {
        int col = ni * 16 + l15;
        #pragma unroll
        for (int r = 0; r < 4; ++r) {
            int row = row0 + w * 16 + l4 * 4 + r;
            if (row < M) P[(size_t)row * 64 + col] = (short)f2bf(accP[ni][r]);
        }
    }
}

// ---------------------------------------------------------------------------
// Plain MFMA GEMM, dual-graph: out[M,128] = act(X @ W + bias).
// ---------------------------------------------------------------------------
template<int K, int AF, int ACT, bool BIAS, bool WF32, bool WB16, bool EMITP>
__global__ __launch_bounds__(256, 2)
void mfma_gemm(const void* __restrict__ X0a, const void* __restrict__ X0b,
               const short* __restrict__ W0t, const float* __restrict__ bias,
               float* __restrict__ outfA, short* __restrict__ outbA,
               float* __restrict__ outfB, short* __restrict__ outbB,
               const short* __restrict__ W56,
               short* __restrict__ PA, short* __restrict__ PB, int M)
{
    constexpr int BK  = 64;
    constexpr int LDA = EMITP ? 136 : 72;
    __shared__ short As[64 * LDA];
    __shared__ short Bs[128 * 72];

    const int half = gridDim.x >> 1;
    int bid = blockIdx.x;
    const int g1 = bid >= half;
    bid -= g1 ? half : 0;
    const void* X0v = g1 ? X0b : X0a;
    float* outf = g1 ? outfB : outfA;
    short* outb = g1 ? outbB : outbA;
    short* P    = g1 ? PB : PA;

    const int t    = threadIdx.x;
    const int row0 = bid * 64;
    const int lane = t & 63;
    const int w    = t >> 6;
    const int wr   = w & 1;
    const int wc   = w >> 1;
    const int l15  = lane & 15;
    const int l4   = lane >> 4;

    f4 acc[2][4];
    #pragma unroll
    for (int i = 0; i < 2; ++i)
        #pragma unroll
        for (int j = 0; j < 4; ++j)
            acc[i][j] = (f4){0.f, 0.f, 0.f, 0.f};

    const int ar = t >> 3;
    const int ac = (t & 7) * 8;

    #pragma unroll 1
    for (int k0 = 0; k0 < K; k0 += BK) {
        __syncthreads();
        #pragma unroll
        for (int p = 0; p < 2; ++p) {
            int r    = ar + p * 32;
            int grow = row0 + r;
            bh8 sv = {0, 0, 0, 0, 0, 0, 0, 0};
            if (AF == 0) {
                if (grow < M) {
                    const float* src = (const float*)X0v + (size_t)grow * K + k0 + ac;
                    float4 v0 = *(const float4*)src;
                    float4 v1 = *(const float4*)(src + 4);
                    sv[0] = (short)f2bf(v0.x); sv[1] = (short)f2bf(v0.y);
                    sv[2] = (short)f2bf(v0.z); sv[3] = (short)f2bf(v0.w);
                    sv[4] = (short)f2bf(v1.x); sv[5] = (short)f2bf(v1.y);
                    sv[6] = (short)f2bf(v1.z); sv[7] = (short)f2bf(v1.w);
                }
            } else {
                if (grow < M)
                    sv = *(const bh8*)((const short*)X0v + (size_t)grow * K + k0 + ac);
            }
            *(bh8*)&As[r * LDA + ac] = sv;
        }
        #pragma unroll
        for (int p = 0; p < 4; ++p) {
            int r = ar + p * 32;
            *(bh8*)&Bs[r * 72 + ac] = *(const bh8*)(W0t + (size_t)r * K + k0 + ac);
        }
        __syncthreads();
        #pragma unroll
        for (int kk = 0; kk < 2; ++kk) {
            bh8 a[2], b[4];
            #pragma unroll
            for (int mi = 0; mi < 2; ++mi)
                a[mi] = *(const bh8*)&As[(wr*32 + mi*16 + l15) * LDA + kk*32 + l4*8];
            #pragma unroll
            for (int ni = 0; ni < 4; ++ni)
                b[ni] = *(const bh8*)&Bs[(wc*64 + ni*16 + l15) * 72 + kk*32 + l4*8];
            #pragma unroll
            for (int mi = 0; mi < 2; ++mi)
                #pragma unroll
                for (int ni = 0; ni < 4; ++ni)
                    acc[mi][ni] = __builtin_amdgcn_mfma_f32_16x16x32_bf16(
                        a[mi], b[ni], acc[mi][ni], 0, 0, 0);
        }
    }

    if (EMITP) __syncthreads();
    #pragma unroll
    for (int mi = 0; mi < 2; ++mi) {
        #pragma unroll
        for (int ni = 0; ni < 4; ++ni) {
            int col = wc * 64 + ni * 16 + l15;
            float bv = BIAS ? bias[col] : 0.f;
            #pragma unroll
            for (int r = 0; r < 4; ++r) {
                int rloc = wr * 32 + mi * 16 + l4 * 4 + r;
                int row  = row0 + rloc;
                float v = act_fn<ACT>(acc[mi][ni][r] + bv);
                unsigned short bb = f2bf(v);
                if (row < M) {
                    if (WF32) outf[(size_t)row * 128 + col] = v;
                    if (WB16) outb[(size_t)row * 128 + col] = (short)bb;
                }
                if (EMITP) As[rloc * LDA + col] = (short)bb;
            }
        }
    }
    if (EMITP) emit_p_phase(As, Bs, W56, P, row0, M, t);
}

// ---------------------------------------------------------------------------
// Fused GraphConv: out = softsign(x @ Wroot + agg @ Wrel), dual-graph.
// Gather phase: per-node straight-line loads, 8-deep ILP.
// DOATT: blocks [convBlocks, convBlocks+attBlocks) instead run the edge
// attention MLP for the NEXT layer (independent work; writes attOut).
// ---------------------------------------------------------------------------
template<int MODE, bool WB16, bool EMITP, bool DOATT>
__global__ __launch_bounds__(256, 2)
void conv_fused(const short* __restrict__ XbA, const short* __restrict__ XbB,
                const int* __restrict__ coffA, const int* __restrict__ coffB,
                const int* __restrict__ crowA, const int* __restrict__ crowB,
                const float* __restrict__ attcA, const float* __restrict__ attcB,
                const short* __restrict__ Wroot, const short* __restrict__ Wrel,
                const short* __restrict__ W56,
                float* __restrict__ outfA, float* __restrict__ outfB,
                short* __restrict__ outbA, short* __restrict__ outbB,
                short* __restrict__ PA, short* __restrict__ PB,
                int convBlocks,
                const int* __restrict__ rowS, const int* __restrict__ colS,
                const int* __restrict__ rowT, const int* __restrict__ colT,
                const int* __restrict__ eposS, const int* __restrict__ eposT,
                const short* __restrict__ PinS, const short* __restrict__ PinT,
                const float* __restrict__ eab1, const float* __restrict__ eaW2,
                const float* __restrict__ eab2, const float* __restrict__ eaW3,
                const float* __restrict__ eab3,
                float* __restrict__ attOutS, float* __restrict__ attOutT,
                int E, int M)
{
    constexpr int LDA = 136;             // full-K agg tile [64][136]
    __shared__ short As[64 * LDA];
    __shared__ short Bs[128 * 72];

    const int t = threadIdx.x;

    // ---- Attention branch (trailing blocks, DOATT only) ----
    if (DOATT && (int)blockIdx.x >= convBlocks) {
        float* ea = (float*)As;          // reuse LDS: 241 floats
        if (t < 200)       ea[t] = eaW2[t];
        else if (t < 210)  ea[t] = eab2[t - 200];
        else if (t < 220)  ea[t] = eaW3[t - 210];
        else if (t < 240)  ea[t] = eab1[t - 220];
        else if (t == 240) ea[240] = eab3[0];
        __syncthreads();
        int idx = ((int)blockIdx.x - convBlocks) * 256 + t;
        if (idx < 2 * E) {
            const int g1 = idx >= E;
            const int e  = idx - (g1 ? E : 0);
            const int* row  = g1 ? rowT  : rowS;
            const int* col  = g1 ? colT  : colS;
            const int* epos = g1 ? eposT : eposS;
            const short* P  = g1 ? PinT  : PinS;
            float* attOut   = g1 ? attOutT : attOutS;
            int r = row[e], c = col[e];
            const unsigned short* p1 = (const unsigned short*)P + (size_t)r * 64;
            const unsigned short* p2 = (const unsigned short*)P + (size_t)c * 64 + 32;
            attOut[epos[e]] = edge_att_mlp(p1, p2, ea, ea + 200, ea + 210, ea + 220, ea[240]);
        }
        return;
    }

    const int half = convBlocks >> 1;
    int bid = blockIdx.x;
    const int g1 = bid >= half;
    bid -= g1 ? half : 0;
    const short* Xb   = g1 ? XbB   : XbA;
    const int*   coff = g1 ? coffB : coffA;
    const int*   crow = g1 ? crowB : crowA;
    const float* attc = g1 ? attcB : attcA;
    float* outf = g1 ? outfB : outfA;
    short* outb = g1 ? outbB : outbA;
    short* P    = g1 ? PB : PA;

    const int row0 = bid * 64;
    const int lane = t & 63;
    const int w    = t >> 6;
    const int wr   = w & 1;
    const int wc   = w >> 1;
    const int l15  = lane & 15;
    const int l4   = lane >> 4;

    // ---- Phase 1: CSR gather, per-node 8-deep straight-line ILP ----
    {
        const int g  = t >> 4;           // 16 groups of 16 lanes
        const int li = t & 15;
        #pragma unroll 1
        for (int q = 0; q < 4; ++q) {
            int rloc = g * 4 + q;
            int n = row0 + rloc;
            float a8[8] = {0.f, 0.f, 0.f, 0.f, 0.f, 0.f, 0.f, 0.f};
            if (n < M) {
                int p  = coff[n];
                int pe = coff[n + 1];
                for (; p + 7 < pe; p += 8) {
                    float w0 = attc[p],     w1 = attc[p + 1];
                    float w2 = attc[p + 2], w3 = attc[p + 3];
                    float w4 = attc[p + 4], w5 = attc[p + 5];
                    float w6 = attc[p + 6], w7 = attc[p + 7];
                    int r0 = crow[p],     r1 = crow[p + 1];
                    int r2 = crow[p + 2], r3 = crow[p + 3];
                    int r4 = crow[p + 4], r5 = crow[p + 5];
                    int r6 = crow[p + 6], r7 = crow[p + 7];
                    w0 = MODE ? fmaf(-0.5f, w0, 1.f) : 0.5f * w0;
                    w1 = MODE ? fmaf(-0.5f, w1, 1.f) : 0.5f * w1;
                    w2 = MODE ? fmaf(-0.5f, w2, 1.f) : 0.5f * w2;
                    w3 = MODE ? fmaf(-0.5f, w3, 1.f) : 0.5f * w3;
                    w4 = MODE ? fmaf(-0.5f, w4, 1.f) : 0.5f * w4;
                    w5 = MODE ? fmaf(-0.5f, w5, 1.f) : 0.5f * w5;
                    w6 = MODE ? fmaf(-0.5f, w6, 1.f) : 0.5f * w6;
                    w7 = MODE ? fmaf(-0.5f, w7, 1.f) : 0.5f * w7;
                    bh8 v0 = *(const bh8*)&Xb[(size_t)r0 * 128 + li * 8];
                    bh8 v1 = *(const bh8*)&Xb[(size_t)r1 * 128 + li * 8];
                    bh8 v2 = *(const bh8*)&Xb[(size_t)r2 * 128 + li * 8];
                    bh8 v3 = *(const bh8*)&Xb[(size_t)r3 * 128 + li * 8];
                    bh8 v4 = *(const bh8*)&Xb[(size_t)r4 * 128 + li * 8];
                    bh8 v5 = *(const bh8*)&Xb[(size_t)r5 * 128 + li * 8];
                    bh8 v6 = *(const bh8*)&Xb[(size_t)r6 * 128 + li * 8];
                    bh8 v7 = *(const bh8*)&Xb[(size_t)r7 * 128 + li * 8];
                    #pragma unroll
                    for (int j = 0; j < 8; ++j) {
                        a8[j] = fmaf(w0, bf2f((unsigned short)v0[j]), a8[j]);
                        a8[j] = fmaf(w1, bf2f((unsigned short)v1[j]), a8[j]);
                        a8[j] = fmaf(w2, bf2f((unsigned short)v2[j]), a8[j]);
                        a8[j] = fmaf(w3, bf2f((unsigned short)v3[j]), a8[j]);
                        a8[j] = fmaf(w4, bf2f((unsigned short)v4[j]), a8[j]);
                        a8[j] = fmaf(w5, bf2f((unsigned short)v5[j]), a8[j]);
                        a8[j] = fmaf(w6, bf2f((unsigned short)v6[j]), a8[j]);
                        a8[j] = fmaf(w7, bf2f((unsigned short)v7[j]), a8[j]);
                    }
                }
                for (; p + 3 < pe; p += 4) {
                    float w0 = attc[p],     w1 = attc[p + 1];
                    float w2 = attc[p + 2], w3 = attc[p + 3];
                    int r0 = crow[p],     r1 = crow[p + 1];
                    int r2 = crow[p + 2], r3 = crow[p + 3];
                    w0 = MODE ? fmaf(-0.5f, w0, 1.f) : 0.5f * w0;
                    w1 = MODE ? fmaf(-0.5f, w1, 1.f) : 0.5f * w1;
                    w2 = MODE ? fmaf(-0.5f, w2, 1.f) : 0.5f * w2;
                    w3 = MODE ? fmaf(-0.5f, w3, 1.f) : 0.5f * w3;
                    bh8 v0 = *(const bh8*)&Xb[(size_t)r0 * 128 + li * 8];
                    bh8 v1 = *(const bh8*)&Xb[(size_t)r1 * 128 + li * 8];
                    bh8 v2 = *(const bh8*)&Xb[(size_t)r2 * 128 + li * 8];
                    bh8 v3 = *(const bh8*)&Xb[(size_t)r3 * 128 + li * 8];
                    #pragma unroll
                    for (int j = 0; j < 8; ++j) {
                        a8[j] = fmaf(w0, bf2f((unsigned short)v0[j]), a8[j]);
                        a8[j] = fmaf(w1, bf2f((unsigned short)v1[j]), a8[j]);
                        a8[j] = fmaf(w2, bf2f((unsigned short)v2[j]), a8[j]);
                        a8[j] = fmaf(w3, bf2f((unsigned short)v3[j]), a8[j]);
                    }
                }
                for (; p < pe; ++p) {
                    float w0 = attc[p];
                    int   r0 = crow[p];
                    w0 = MODE ? fmaf(-0.5f, w0, 1.f) : 0.5f * w0;
                    bh8 v0 = *(const bh8*)&Xb[(size_t)r0 * 128 + li * 8];
                    #pragma unroll
                    for (int j = 0; j < 8; ++j)
                        a8[j] = fmaf(w0, bf2f((unsigned short)v0[j]), a8[j]);
                }
            }
            bh8 o;
            #pragma unroll
            for (int j = 0; j < 8; ++j) o[j] = (short)f2bf(a8[j]);
            *(bh8*)&As[rloc * LDA + li * 8] = o;
        }
    }
    __syncthreads();

    f4 acc[2][4];
    #pragma unroll
    for (int i = 0; i < 2; ++i)
        #pragma unroll
        for (int j = 0; j < 4; ++j)
            acc[i][j] = (f4){0.f, 0.f, 0.f, 0.f};

    const int ar = t >> 3;
    const int ac = (t & 7) * 8;

    // ---- Phase 2: agg @ Wrel ----
    #pragma unroll 1
    for (int k0 = 0; k0 < 128; k0 += 64) {
        if (k0) __syncthreads();
        #pragma unroll
        for (int p = 0; p < 4; ++p) {
            int r = ar + p * 32;
            *(bh8*)&Bs[r * 72 + ac] = *(const bh8*)(Wrel + (size_t)r * 128 + k0 + ac);
        }
        __syncthreads();
        #pragma unroll
        for (int kk = 0; kk < 2; ++kk) {
            bh8 a[2], b[4];
            #pragma unroll
            for (int mi = 0; mi < 2; ++mi)
                a[mi] = *(const bh8*)&As[(wr*32 + mi*16 + l15) * LDA + k0 + kk*32 + l4*8];
            #pragma unroll
            for (int ni = 0; ni < 4; ++ni)
                b[ni] = *(const bh8*)&Bs[(wc*64 + ni*16 + l15) * 72 + kk*32 + l4*8];
            #pragma unroll
            for (int mi = 0; mi < 2; ++mi)
                #pragma unroll
                for (int ni = 0; ni < 4; ++ni)
                    acc[mi][ni] = __builtin_amdgcn_mfma_f32_16x16x32_bf16(
                        a[mi], b[ni], acc[mi][ni], 0, 0, 0);
        }
    }

    // ---- Phase 3: x @ Wroot ----
    #pragma unroll 1
    for (int k0 = 0; k0 < 128; k0 += 64) {
        __syncthreads();
        #pragma unroll
        for (int p = 0; p < 2; ++p) {
            int r    = ar + p * 32;
            int grow = row0 + r;
            bh8 sv = {0, 0, 0, 0, 0, 0, 0, 0};
            if (grow < M)
                sv = *(const bh8*)(Xb + (size_t)grow * 128 + k0 + ac);
            *(bh8*)&As[r * LDA + ac] = sv;
        }
        #pragma unroll
        for (int p = 0; p < 4; ++p) {
            int r = ar + p * 32;
            *(bh8*)&Bs[r * 72 + ac] = *(const bh8*)(Wroot + (size_t)r * 128 + k0 + ac);
        }
        __syncthreads();
        #pragma unroll
        for (int kk = 0; kk < 2; ++kk) {
            bh8 a[2], b[4];
            #pragma unroll
            for (int mi = 0; mi < 2; ++mi)
                a[mi] = *(const bh8*)&As[(wr*32 + mi*16 + l15) * LDA + kk*32 + l4*8];
            #pragma unroll
            for (int ni = 0; ni < 4; ++ni)
                b[ni] = *(const bh8*)&Bs[(wc*64 + ni*16 + l15) * 72 + kk*32 + l4*8];
            #pragma unroll
            for (int mi = 0; mi < 2; ++mi)
                #pragma unroll
                for (int ni = 0; ni < 4; ++ni)
                    acc[mi][ni] = __builtin_amdgcn_mfma_f32_16x16x32_bf16(
                        a[mi], b[ni], acc[mi][ni], 0, 0, 0);
        }
    }

    // ---- Epilogue (+ optional P emission) ----
    if (EMITP) __syncthreads();
    #pragma unroll
    for (int mi = 0; mi < 2; ++mi) {
        #pragma unroll
        for (int ni = 0; ni < 4; ++ni) {
            int col = wc * 64 + ni * 16 + l15;
            #pragma unroll
            for (int r = 0; r < 4; ++r) {
                int rloc = wr * 32 + mi * 16 + l4 * 4 + r;
                int row  = row0 + rloc;
                float v = act_fn<2>(acc[mi][ni][r]);
                unsigned short bb = f2bf(v);
                if (row < M) {
                    outf[(size_t)row * 128 + col] = v;
                    if (WB16) outb[(size_t)row * 128 + col] = (short)bb;
                }
                if (EMITP) As[rloc * LDA + col] = (short)bb;
            }
        }
    }
    if (EMITP) emit_p_phase(As, Bs, W56, P, row0, M, t);
}

// ---------------------------------------------------------------------------
// Weight prep + degree histogram, one dispatch (independent block ranges).
// ---------------------------------------------------------------------------
__global__ void prep_hist(const float* __restrict__ eaW1, const float* __restrict__ fxW1,
                          const float* __restrict__ fxW2, const float* __restrict__ convWroot,
                          const float* __restrict__ convWrel,
                          short* __restrict__ w56, short* __restrict__ fxW1t,
                          short* __restrict__ fxW2t, short* __restrict__ wrt,
                          short* __restrict__ wlt,
                          const int* __restrict__ colS, const int* __restrict__ colT,
                          int* __restrict__ deg, int N, int E, int prepBlocks)
{
    if ((int)blockIdx.x >= prepBlocks) {
        int idx = (blockIdx.x - prepBlocks) * 256 + threadIdx.x;
        if (idx >= 2 * E) return;
        const int g1 = idx >= E;
        const int e  = idx - (g1 ? E : 0);
        int c = (g1 ? colT : colS)[e];
        atomicAdd(&deg[(size_t)g1 * N + c], 1);
        return;
    }
    int i = blockIdx.x * 256 + threadIdx.x;
    if (i < 64 * 128) {
        int j = i >> 7, k = i & 127;
        float v = 0.f;
        if (j < 20)                  v = eaW1[k * 20 + j];
        else if (j >= 32 && j < 52)  v = eaW1[(128 + k) * 20 + (j - 32)];
        w56[i] = (short)f2bf(v);
        return;
    }
    i -= 64 * 128;
    if (i < 512 * 128) {
        int k = i >> 7, n = i & 127;
        fxW1t[(size_t)n * 512 + k] = (short)f2bf(fxW1[i]);
        return;
    }
    i -= 512 * 128;
    if (i < 128 * 128) {
        int k = i >> 7, n = i & 127;
        fxW2t[n * 128 + k] = (short)f2bf(fxW2[i]);
        return;
    }
    i -= 128 * 128;
    if (i < 2 * 128 * 128) {
        int L = i >> 14, r = i & 16383;
        int k = r >> 7, n = r & 127;
        wrt[L * 16384 + n * 128 + k] = (short)f2bf(convWroot[i]);
        return;
    }
    i -= 2 * 128 * 128;
    if (i < 2 * 128 * 128) {
        int L = i >> 14, r = i & 16383;
        int k = r >> 7, n = r & 127;
        wlt[L * 16384 + n * 128 + k] = (short)f2bf(convWrel[i]);
    }
}

// ---------------------------------------------------------------------------
// CSR build: scan kernels (hist lives in prep_hist)
// ---------------------------------------------------------------------------
__device__ __forceinline__ int block_incl_scan(int v, int* wsum)
{
    int lane = threadIdx.x & 63;
    int w    = threadIdx.x >> 6;
    #pragma unroll
    for (int off = 1; off < 64; off <<= 1) {
        int t = __shfl_up(v, off);
        if (lane >= off) v += t;
    }
    if (lane == 63) wsum[w] = v;
    __syncthreads();
    int add = 0;
    for (int j = 0; j < w; ++j) add += wsum[j];
    return v + add;
}

__global__ __launch_bounds__(256)
void scanA_both(const int* __restrict__ deg, int* __restrict__ coffS,
                int* __restrict__ coffT, int* __restrict__ bsum, int N)
{
    __shared__ int wsum[4];
    int gy = blockIdx.y;
    const int* d = deg + (size_t)gy * N;
    int* coff    = gy ? coffT : coffS;
    int* bs      = bsum + gy * 256;
    int i = blockIdx.x * 256 + threadIdx.x;
    int orig = (i < N) ? d[i] : 0;
    int v = block_incl_scan(orig, wsum);
    if (i < N) coff[i] = v - orig;
    if (threadIdx.x == 255) bs[blockIdx.x] = v;
}

__global__ __launch_bounds__(256)
void scanB_both(const int* __restrict__ bsum, int* __restrict__ boff, int nb)
{
    __shared__ int wsum[4];
    int gy = blockIdx.y;
    const int* bs = bsum + gy * 256;
    int* bo       = boff + gy * 256;
    int tid = threadIdx.x;
    int orig = (tid < nb) ? bs[tid] : 0;
    int v = block_incl_scan(orig, wsum);
    if (tid < nb) bo[tid] = v - orig;
}

__global__ __launch_bounds__(256)
void scanC_both(int* __restrict__ coffS, int* __restrict__ coffT,
                const int* __restrict__ boff, int* __restrict__ curS,
                int* __restrict__ curT, int N, int E)
{
    int gy = blockIdx.y;
    int* coff = gy ? coffT : coffS;
    int* cur  = gy ? curT  : curS;
    const int* bo = boff + gy * 256;
    int i = blockIdx.x * 256 + threadIdx.x;
    if (i < N) {
        int v = coff[i] + bo[i >> 8];
        coff[i] = v;
        cur[i]  = v;
    }
    if (i == 0) coff[N] = E;
}

// ---------------------------------------------------------------------------
// CSR cursor fill + L0 edge attention, fused.
// ---------------------------------------------------------------------------
__global__ __launch_bounds__(256)
void fill_att_both(const int* __restrict__ rowS, const int* __restrict__ colS,
                   const int* __restrict__ rowT, const int* __restrict__ colT,
                   int* __restrict__ curS, int* __restrict__ curT,
                   int* __restrict__ crowS, int* __restrict__ crowT,
                   int* __restrict__ eposS, int* __restrict__ eposT,
                   const short* __restrict__ PS, const short* __restrict__ PT,
                   const float* __restrict__ eab1, const float* __restrict__ eaW2,
                   const float* __restrict__ eab2, const float* __restrict__ eaW3,
                   const float* __restrict__ eab3,
                   float* __restrict__ attcS, float* __restrict__ attcT, int E)
{
    __shared__ float w2[200], b2s[10], w3s[10], sb1[20], sb3;
    int t = threadIdx.x;
    if (t < 200) w2[t] = eaW2[t];
    if (t < 20)  sb1[t] = eab1[t];
    if (t < 10)  { b2s[t] = eab2[t]; w3s[t] = eaW3[t]; }
    if (t == 0)  sb3 = eab3[0];
    __syncthreads();

    int idx = blockIdx.x * 256 + t;
    if (idx >= 2 * E) return;
    const int g1 = idx >= E;
    const int e  = idx - (g1 ? E : 0);
    const int* row = g1 ? rowT : rowS;
    const int* col = g1 ? colT : colS;
    int* cur  = g1 ? curT  : curS;
    int* crow = g1 ? crowT : crowS;
    int* epos = g1 ? eposT : eposS;
    const short* P = g1 ? PT : PS;
    float* attc    = g1 ? attcT : attcS;

    int c = col[e];
    int r = row[e];
    int p = atomicAdd(&cur[c], 1);
    crow[p] = r;
    epos[e] = p;

    const unsigned short* p1 = (const unsigned short*)P + (size_t)r * 64;
    const unsigned short* p2 = (const unsigned short*)P + (size_t)c * 64 + 32;
    attc[p] = edge_att_mlp(p1, p2, w2, b2s, w3s, sb1, sb3);
}

// ---------------------------------------------------------------------------

extern "C" void kernel_launch(void* const* d_in, const int* in_sizes, int n_in,
                              void* d_out, int out_size, void* d_ws, size_t ws_size,
                              hipStream_t stream)
{
    const float* src_fea = (const float*)d_in[0];
    const float* trg_fea = (const float*)d_in[1];
    const int*   src_row = (const int*)d_in[2];
    const int*   src_col = (const int*)d_in[3];
    const int*   trg_row = (const int*)d_in[4];
    const int*   trg_col = (const int*)d_in[5];
    const float* fxW1 = (const float*)d_in[6];
    const float* fxb1 = (const float*)d_in[7];
    const float* fxW2 = (const float*)d_in[8];
    const float* fxb2 = (const float*)d_in[9];
    const float* eaW1 = (const float*)d_in[10];
    const float* eab1 = (const float*)d_in[11];
    const float* eaW2 = (const float*)d_in[12];
    const float* eab2 = (const float*)d_in[13];
    const float* eaW3 = (const float*)d_in[14];
    const float* eab3 = (const float*)d_in[15];
    const float* convWroot = (const float*)d_in[16];
    const float* convWrel  = (const float*)d_in[17];

    const int N = in_sizes[0] / 512;
    const int E = in_sizes[2];

    float* out = (float*)d_out;
    const size_t slot_sz = (size_t)N * 128;
    auto slot = [&](int i) { return out + (size_t)i * slot_sz; };

    // ---- workspace layout ----
    float* fp     = (float*)d_ws;
    float* attcS0 = fp; fp += E;
    float* attcT0 = fp; fp += E;
    float* attcS1 = fp; fp += E;
    float* attcT1 = fp; fp += E;
    int* ip    = (int*)fp;
    int* deg   = ip; ip += 2 * N;
    int* bsum  = ip; ip += 512;
    int* boff  = ip; ip += 512;
    int* coffS = ip; ip += N + 2;
    int* coffT = ip; ip += N + 2;
    int* curS  = ip; ip += N;
    int* curT  = ip; ip += N;
    int* crowS = ip; ip += E;
    int* crowT = ip; ip += E;
    int* eposS = ip; ip += E;
    int* eposT = ip; ip += E;
    short* sp = (short*)((((uintptr_t)ip) + 255) & ~(uintptr_t)255);
    short* xb0   = sp; sp += slot_sz;            // bf16 src1
    short* xb1   = sp; sp += slot_sz;            // bf16 trg1
    short* xsbS[2]; short* xsbT[2];
    xsbS[0] = sp; sp += slot_sz;
    xsbS[1] = sp; sp += slot_sz;
    xsbT[0] = sp; sp += slot_sz;
    xsbT[1] = sp; sp += slot_sz;
    short* PS    = sp; sp += (size_t)N * 64;     // bf16 projections, stride 64
    short* PT    = sp; sp += (size_t)N * 64;
    short* w56   = sp; sp += 64 * 128;
    short* fxW1t = sp; sp += 128 * 512;
    short* fxW2t = sp; sp += 128 * 128;
    short* wrt   = sp; sp += 2 * 128 * 128;
    short* wlt   = sp; sp += 2 * 128 * 128;

    const int e2grid  = (2 * E + 255) / 256;
    const int nchunks = (N + 255) / 256;

    // ---- weight prep + degree histogram (one dispatch; deg zeroed first) ----
    hipMemsetAsync(deg, 0, (size_t)2 * N * sizeof(int), stream);
    const int prep_total = 64*128 + 512*128 + 128*128 + 2*128*128 + 2*128*128;
    const int prepBlocks = (prep_total + 255) / 256;
    prep_hist<<<prepBlocks + e2grid, 256, 0, stream>>>(
        eaW1, fxW1, fxW2, convWroot, convWrel, w56, fxW1t, fxW2t, wrt, wlt,
        src_col, trg_col, deg, N, E, prepBlocks);

    const int gb = (N + 63) / 64;
    short* hS = xsbS[0];   // fx hidden, dead until L0 conv writes
    short* hT = xsbT[0];
    // fx layer 1 (fp32 in, bf16 h out)
    mfma_gemm<512, 0, 1, true, false, true, false><<<2 * gb, 256, 0, stream>>>(
        src_fea, trg_fea, fxW1t, fxb1,
        nullptr, hS, nullptr, hT, nullptr, nullptr, nullptr, N);
    // fx layer 2 (+ emit P for L0 attention)
    mfma_gemm<128, 1, 1, true, true, true, true><<<2 * gb, 256, 0, stream>>>(
        hS, hT, fxW2t, fxb2,
        slot(0), xb0, slot(3), xb1, w56, PS, PT, N);

    // ---- CSR scan + fused fill/att(L0), both graphs ----
    scanA_both<<<dim3(nchunks, 2), 256, 0, stream>>>(deg, coffS, coffT, bsum, N);
    scanB_both<<<dim3(1, 2), 256, 0, stream>>>(bsum, boff, nchunks);
    scanC_both<<<dim3(nchunks, 2), 256, 0, stream>>>(coffS, coffT, boff, curS, curT, N, E);
    fill_att_both<<<e2grid, 256, 0, stream>>>(
        src_row, src_col, trg_row, trg_col, curS, curT, crowS, crowT,
        eposS, eposT, PS, PT, eab1, eaW2, eab2, eaW3, eab3, attcS0, attcT0, E);

    const short* WrT0 = wrt;
    const short* WlT0 = wlt;
    const short* WrT1 = wrt + 16384;
    const short* WlT1 = wlt + 16384;

    // ---- Layer 0 ----
    // xs0 = softsign(x @ Wroot0 + agg_wc(attc0) @ Wrel0); emits P(xs0)
    conv_fused<0, true, true, false><<<2 * gb, 256, 0, stream>>>(
        xb0, xb1, coffS, coffT, crowS, crowT, attcS0, attcT0,
        WrT0, WlT0, w56, slot(1), slot(4), xsbS[0], xsbT[0], PS, PT,
        2 * gb, nullptr, nullptr, nullptr, nullptr, nullptr, nullptr,
        nullptr, nullptr, nullptr, nullptr, nullptr, nullptr, nullptr,
        nullptr, nullptr, E, N);

    // cf0 = softsign(xs0 @ Wroot0 + agg_wo(attc0) @ Wrel0)
    //   + trailing blocks: edge attention for L1 from P(xs0) -> attc1
    conv_fused<1, false, false, true><<<2 * gb + e2grid, 256, 0, stream>>>(
        xsbS[0], xsbT[0], coffS, coffT, crowS, crowT, attcS0, attcT0,
        WrT0, WlT0, nullptr, slot(6), slot(8), nullptr, nullptr, nullptr, nullptr,
        2 * gb, src_row, src_col, trg_row, trg_col, eposS, eposT,
        PS, PT, eab1, eaW2, eab2, eaW3, eab3, attcS1, attcT1, E, N);

    // ---- Layer 1 ----
    // xs1 = softsign(xs0 @ Wroot1 + agg_wc(attc1) @ Wrel1)
    conv_fused<0, true, false, false><<<2 * gb, 256, 0, stream>>>(
        xsbS[0], xsbT[0], coffS, coffT, crowS, crowT, attcS1, attcT1,
        WrT1, WlT1, nullptr, slot(2), slot(5), xsbS[1], xsbT[1], nullptr, nullptr,
        2 * gb, nullptr, nullptr, nullptr, nullptr, nullptr, nullptr,
        nullptr, nullptr, nullptr, nullptr, nullptr, nullptr, nullptr,
        nullptr, nullptr, E, N);

    // cf1 = softsign(xs1 @ Wroot1 + agg_wo(attc1) @ Wrel1)
    conv_fused<1, false, false, false><<<2 * gb, 256, 0, stream>>>(
        xsbS[1], xsbT[1], coffS, coffT, crowS, crowT, attcS1, attcT1,
        WrT1, WlT1, nullptr, slot(7), slot(9), nullptr, nullptr, nullptr, nullptr,
        2 * gb, nullptr, nullptr, nullptr, nullptr, nullptr, nullptr,
        nullptr, nullptr, nullptr, nullptr, nullptr, nullptr, nullptr,
        nullptr, nullptr, E, N);
}